// Round 13
// baseline (95.571 us; speedup 1.0000x reference)
//
#include <hip/hip_runtime.h>

#define NR    8192
#define ALPHA 0.2f
#define NCH   512          // chunks of 16 ranks
#define CSZ   16
#define NSC   16           // superchunks of 32 chunks (512 ranks)
#define ZN    (NCH * 65 * 2 + NSC * 65 * 2)   // floats to zero = 68640

__device__ inline unsigned enc_f32(float f) {
    unsigned u = __float_as_uint(f);
    return (u & 0x80000000u) ? ~u : (u | 0x80000000u);
}
__device__ inline float dec_f32(unsigned u) {
    return __uint_as_float((u & 0x80000000u) ? (u ^ 0x80000000u) : ~u);
}

// kA: H = X@W, f1, f2->enc key. 512 blocks x 16 rows (R11 layout).
// Also zeroes the CHPQ/SCHPQ accumulators (graph edge orders this before kB).
__global__ __launch_bounds__(256) void kA(
    const float* __restrict__ X, const float* __restrict__ W, const float* __restrict__ aa,
    float* __restrict__ H, float* __restrict__ F1, unsigned* __restrict__ ENC,
    float* __restrict__ ZERO)
{
    __shared__ __align__(16) float xs[16 * 128];   // 8 KB
    __shared__ float part[16 * 4 * 64];            // 16 KB
    const int tid = threadIdx.x, w = tid >> 6, c = tid & 63;
    const int R0 = blockIdx.x * 16;

    const int g = blockIdx.x * 256 + tid;
    if (g < ZN) ZERO[g] = 0.f;

    float Wreg[32];
#pragma unroll
    for (int e = 0; e < 32; ++e) Wreg[e] = W[(w * 32 + e) * 64 + c];
    {
        const float4* X4 = (const float4*)(X + R0 * 128);
        float4* xs4 = (float4*)xs;
        xs4[tid] = X4[tid];
        xs4[256 + tid] = X4[256 + tid];
    }
    __syncthreads();

    for (int r = 0; r < 16; ++r) {
        const float4* xr4 = (const float4*)&xs[r * 128 + w * 32];
        float acc = 0.f;
#pragma unroll
        for (int e = 0; e < 8; ++e) {
            float4 xv = xr4[e];
            acc = fmaf(xv.x, Wreg[e * 4 + 0], acc);
            acc = fmaf(xv.y, Wreg[e * 4 + 1], acc);
            acc = fmaf(xv.z, Wreg[e * 4 + 2], acc);
            acc = fmaf(xv.w, Wreg[e * 4 + 3], acc);
        }
        part[(r * 4 + w) * 64 + c] = acc;
    }
    __syncthreads();

    const float a1 = aa[c], a2 = aa[64 + c];
    for (int rr = 0; rr < 4; ++rr) {
        const int r = w * 4 + rr, i = R0 + r;
        float h = part[(r * 4 + 0) * 64 + c] + part[(r * 4 + 1) * 64 + c]
                + part[(r * 4 + 2) * 64 + c] + part[(r * 4 + 3) * 64 + c];
        H[i * 64 + c] = h;
        float v1 = h * a1, v2 = h * a2;
#pragma unroll
        for (int m = 32; m >= 1; m >>= 1) {
            v1 += __shfl_xor(v1, m, 64);
            v2 += __shfl_xor(v2, m, 64);
        }
        if (c == 0) { F1[i] = v1; ENC[i] = enc_f32(v2); }
    }
}

// kB: exact ranks (64-bit sortkeys, registers) + fm + scatter SPQJ/cs +
// ATOMIC chunk & superchunk sums of P*h, Q*h (replaces the scan kernel).
// 1024 blocks x 8 j's.
__global__ __launch_bounds__(256) void kB(
    const unsigned* __restrict__ ENC, const float* __restrict__ H,
    float4* __restrict__ SPQJ, float* __restrict__ cs, float* __restrict__ FMf,
    float* __restrict__ CHPQ, float* __restrict__ SCHPQ)
{
    __shared__ unsigned cw[4 * 8];
    __shared__ unsigned rks[8];
    __shared__ float pqs[8][2];
    const int tid = threadIdx.x, bid = blockIdx.x;
    const uint4* E4 = (const uint4*)ENC;

    unsigned long long k64[32];
    unsigned mx = 0;
    {
        const unsigned base = tid * 4;
#pragma unroll
        for (int q = 0; q < 8; ++q) {
            uint4 v = E4[q * 256 + tid];
            mx = max(max(mx, v.x), max(max(v.y, v.z), v.w));
            const unsigned ib = q * 1024 + base;
            k64[q * 4 + 0] = ((unsigned long long)v.x << 13) | (ib + 0);
            k64[q * 4 + 1] = ((unsigned long long)v.y << 13) | (ib + 1);
            k64[q * 4 + 2] = ((unsigned long long)v.z << 13) | (ib + 2);
            k64[q * 4 + 3] = ((unsigned long long)v.w << 13) | (ib + 3);
        }
    }
#pragma unroll
    for (int m = 32; m >= 1; m >>= 1)
        mx = max(mx, (unsigned)__shfl_xor((int)mx, m, 64));
    if ((tid & 63) == 0) cw[tid >> 6] = mx;
    __syncthreads();
    const float fm = dec_f32(max(max(cw[0], cw[1]), max(cw[2], cw[3])));
    __syncthreads();

    unsigned cnt[8];
#pragma unroll
    for (int jj = 0; jj < 8; ++jj) {
        const int j = bid * 8 + jj;                          // block-uniform
        const unsigned long long th = ((unsigned long long)ENC[j] << 13) | (unsigned)j;
        unsigned cjj = 0;
#pragma unroll
        for (int q = 0; q < 32; ++q) cjj += (unsigned)(k64[q] < th);
        cnt[jj] = cjj;
    }
#pragma unroll
    for (int jj = 0; jj < 8; ++jj) {
        unsigned v = cnt[jj];
#pragma unroll
        for (int m = 32; m >= 1; m >>= 1) v += (unsigned)__shfl_xor((int)v, m, 64);
        cnt[jj] = v;
    }
    const int w = tid >> 6;
    if ((tid & 63) == 0) {
#pragma unroll
        for (int jj = 0; jj < 8; ++jj) cw[w * 8 + jj] = cnt[jj];
    }
    __syncthreads();
    if (tid < 8) {
        const unsigned r = cw[tid] + cw[8 + tid] + cw[16 + tid] + cw[24 + tid];
        const int j = bid * 8 + tid;
        const float f = dec_f32(ENC[j]);
        const float d = f - fm;
        const float P = __expf(d), Q = __expf(ALPHA * d);
        SPQJ[r] = make_float4(f, P, Q, __int_as_float(j));
        if ((r & (CSZ - 1)) == 0) cs[r >> 4] = f;
        rks[tid] = r;
        pqs[tid][0] = P; pqs[tid][1] = Q;
    }
    if (bid == 0 && tid == 0) FMf[0] = fm;
    __syncthreads();

    // atomic accumulation: wave w handles j's 2w, 2w+1
    const int c = tid & 63;
#pragma unroll
    for (int e = 0; e < 2; ++e) {
        const int jj = w * 2 + e;
        const int j = bid * 8 + jj;
        const unsigned r = rks[jj];
        const float P = pqs[jj][0], Q = pqs[jj][1];
        const int ch = r >> 4, sc = r >> 9;
        const float hv = H[j * 64 + c];
        atomicAdd(&CHPQ[(ch * 65 + c) * 2 + 0], P * hv);
        atomicAdd(&CHPQ[(ch * 65 + c) * 2 + 1], Q * hv);
        atomicAdd(&SCHPQ[(sc * 65 + c) * 2 + 0], P * hv);
        atomicAdd(&SCHPQ[(sc * 65 + c) * 2 + 1], Q * hv);
        if (c == 0) {
            atomicAdd(&CHPQ[(ch * 65 + 64) * 2 + 0], P);
            atomicAdd(&CHPQ[(ch * 65 + 64) * 2 + 1], Q);
            atomicAdd(&SCHPQ[(sc * 65 + 64) * 2 + 0], P);
            atomicAdd(&SCHPQ[(sc * 65 + 64) * 2 + 1], Q);
        }
    }
}

// kD: per-row bsearch (512-entry cs in LDS) + two-level prefix assembly
// (<=16 superchunk + <=32 chunk float2 loads) + 16-elem exact exclusion +
// elu. 2048 blocks x 4 rows (1 row/wave).
__global__ __launch_bounds__(256) void kD(
    const float* __restrict__ H, const float* __restrict__ F1,
    const float4* __restrict__ SPQJ, const float* __restrict__ cs,
    const float* __restrict__ FMf,
    const float2* __restrict__ CHPQ2, const float2* __restrict__ SCHPQ2,
    float* __restrict__ OUT)
{
    __shared__ float sb[NCH];
    const int tid = threadIdx.x, w = tid >> 6, c = tid & 63, bid = blockIdx.x;
    sb[tid] = cs[tid];
    sb[256 + tid] = cs[256 + tid];
    __syncthreads();

    const float fm = FMf[0];
    const int i = bid * 4 + w;
    const float f1 = F1[i];
    const float s = f1 + fm;
    const float mrow = fmaxf(s, ALPHA * s);
    const float A = __expf(s - mrow);
    const float B = __expf(ALPHA * s - mrow);
    const float th = -f1;

    int lo = 0, hi = NCH;
    while (lo < hi) { int mid = (lo + hi) >> 1; if (sb[mid] < th) lo = mid + 1; else hi = mid; }
    const int b = lo > 0 ? lo - 1 : 0;
    const int S = b >> 5;                       // superchunk of boundary chunk

    float Ptot = 0.f, ptot = 0.f;
    float pp = 0.f, ps = 0.f, qv = 0.f, qs = 0.f;
#pragma unroll
    for (int s2 = 0; s2 < NSC; ++s2) {
        const float2 v  = SCHPQ2[s2 * 65 + c];
        const float2 vs = SCHPQ2[s2 * 65 + 64];
        Ptot += v.x; ptot += vs.x;
        if (s2 < S) { pp += v.x; ps += vs.x; qv += v.y; qs += vs.y; }
    }
    for (int k = S << 5; k <= b; ++k) {
        const float2 v  = CHPQ2[k * 65 + c];
        const float2 vs = CHPQ2[k * 65 + 64];
        pp += v.x; ps += vs.x; qv += v.y; qs += vs.y;
    }
    // pp/qv now include ALL of chunk b; subtract elements with sv >= th.
    const int t0 = b << 4;
#pragma unroll
    for (int e = 0; e < CSZ; ++e) {
        const float4 v = SPQJ[t0 + e];          // wave-uniform 16B broadcast
        const int jv = __float_as_int(v.w);
        const float hv = H[jv * 64 + c];
        const bool ex = !(v.x < th);
        const float sP = ex ? v.y : 0.f, sQ = ex ? v.z : 0.f;
        pp = fmaf(-sP, hv, pp); ps -= sP;
        qv = fmaf(-sQ, hv, qv); qs -= sQ;
    }
    const float Pvec = Ptot - pp;
    const float pden = ptot - ps;
    const float num = A * Pvec + B * qv;
    const float den = A * pden + B * qs;
    const float feat = num / den;
    OUT[i * 64 + c] = feat > 0.f ? feat : expm1f(feat);
}

extern "C" void kernel_launch(void* const* d_in, const int* in_sizes, int n_in,
                              void* d_out, int out_size, void* d_ws, size_t ws_size,
                              hipStream_t stream) {
    const float* X = (const float*)d_in[0];   // 8192 x 128
    const float* W = (const float*)d_in[1];   // 128 x 64
    const float* a = (const float*)d_in[2];   // 128 x 1
    float* OUT = (float*)d_out;               // 8192 x 64

    float*    ws    = (float*)d_ws;
    float*    H     = ws;                        // 524288
    float*    F1    = H + 524288;                // 8192
    unsigned* ENC   = (unsigned*)(F1 + 8192);    // 8192
    float*    FMf   = (float*)(ENC + 8192);      // 16 (1 used)
    float*    cs    = FMf + 16;                  // 512
    float4*   SPQJ  = (float4*)(cs + 512);       // 8192 float4 (16B-aligned)
    float*    CHPQ  = (float*)(SPQJ + 8192);     // 512*65*2
    float*    SCHPQ = CHPQ + NCH * 65 * 2;       // 16*65*2  (contiguous w/ CHPQ)

    kA<<<512,  256, 0, stream>>>(X, W, a, H, F1, ENC, CHPQ);
    kB<<<1024, 256, 0, stream>>>(ENC, H, SPQJ, cs, FMf, CHPQ, SCHPQ);
    kD<<<2048, 256, 0, stream>>>(H, F1, SPQJ, cs, FMf,
                                 (const float2*)CHPQ, (const float2*)SCHPQ, OUT);
}

// Round 14
// 39.036 us; speedup vs baseline: 2.4483x; 2.4483x over previous
//
#include <hip/hip_runtime.h>

#define NR    8192
#define ALPHA 0.2f
#define NCH   512          // chunks
#define CSZ   16           // elements per chunk

__device__ inline unsigned enc_f32(float f) {
    unsigned u = __float_as_uint(f);
    return (u & 0x80000000u) ? ~u : (u | 0x80000000u);
}
__device__ inline float dec_f32(unsigned u) {
    return __uint_as_float((u & 0x80000000u) ? (u ^ 0x80000000u) : ~u);
}

// kA: H = X@W (row-major AND column-major HT), f1, f2->enc key.
// 512 blocks x 16 rows. HT built via padded LDS transpose ([64][17]) so
// kC34's per-column gathers read fully-used contiguous lines.
__global__ __launch_bounds__(256) void kA(
    const float* __restrict__ X, const float* __restrict__ W, const float* __restrict__ aa,
    float* __restrict__ H, float* __restrict__ HT, float* __restrict__ F1,
    unsigned* __restrict__ ENC)
{
    __shared__ __align__(16) float xs[16 * 128];   // 8 KB
    __shared__ float part[16 * 4 * 64];            // 16 KB
    __shared__ float htl[64 * 17];                 // 4.25 KB (17-pad: no bank conflicts)
    const int tid = threadIdx.x, w = tid >> 6, c = tid & 63;
    const int R0 = blockIdx.x * 16;

    float Wreg[32];
#pragma unroll
    for (int e = 0; e < 32; ++e) Wreg[e] = W[(w * 32 + e) * 64 + c];
    {
        const float4* X4 = (const float4*)(X + R0 * 128);
        float4* xs4 = (float4*)xs;
        xs4[tid] = X4[tid];
        xs4[256 + tid] = X4[256 + tid];
    }
    __syncthreads();

    for (int r = 0; r < 16; ++r) {
        const float4* xr4 = (const float4*)&xs[r * 128 + w * 32];
        float acc = 0.f;
#pragma unroll
        for (int e = 0; e < 8; ++e) {
            float4 xv = xr4[e];
            acc = fmaf(xv.x, Wreg[e * 4 + 0], acc);
            acc = fmaf(xv.y, Wreg[e * 4 + 1], acc);
            acc = fmaf(xv.z, Wreg[e * 4 + 2], acc);
            acc = fmaf(xv.w, Wreg[e * 4 + 3], acc);
        }
        part[(r * 4 + w) * 64 + c] = acc;
    }
    __syncthreads();

    const float a1 = aa[c], a2 = aa[64 + c];
    for (int rr = 0; rr < 4; ++rr) {
        const int r = w * 4 + rr, i = R0 + r;
        float h = part[(r * 4 + 0) * 64 + c] + part[(r * 4 + 1) * 64 + c]
                + part[(r * 4 + 2) * 64 + c] + part[(r * 4 + 3) * 64 + c];
        H[i * 64 + c] = h;
        htl[c * 17 + r] = h;
        float v1 = h * a1, v2 = h * a2;
#pragma unroll
        for (int m = 32; m >= 1; m >>= 1) {
            v1 += __shfl_xor(v1, m, 64);
            v2 += __shfl_xor(v2, m, 64);
        }
        if (c == 0) { F1[i] = v1; ENC[i] = enc_f32(v2); }
    }
    __syncthreads();
    {
        const int ct = tid >> 2, rq = tid & 3;     // column ct, row-quad rq
        float4 v = make_float4(htl[ct * 17 + rq * 4 + 0], htl[ct * 17 + rq * 4 + 1],
                               htl[ct * 17 + rq * 4 + 2], htl[ct * 17 + rq * 4 + 3]);
        *(float4*)&HT[ct * NR + R0 + rq * 4] = v;  // coalesced 16B column stores
    }
}

// kB: exact tie-broken ranks via 64-bit sortkeys (enc<<13|idx), registers only.
// 1024 blocks x 8 j's. Thresholds block-uniform (scalar path). 32 keys/thread.
__global__ __launch_bounds__(256) void kB(
    const unsigned* __restrict__ ENC, float* __restrict__ SF2, int* __restrict__ PERM)
{
    __shared__ unsigned cw[4 * 8];
    const int tid = threadIdx.x, bid = blockIdx.x;
    const uint4* E4 = (const uint4*)ENC;

    unsigned long long k64[32];
    {
        const unsigned base = tid * 4;
#pragma unroll
        for (int q = 0; q < 8; ++q) {
            uint4 v = E4[q * 256 + tid];
            const unsigned ib = q * 1024 + base;
            k64[q * 4 + 0] = ((unsigned long long)v.x << 13) | (ib + 0);
            k64[q * 4 + 1] = ((unsigned long long)v.y << 13) | (ib + 1);
            k64[q * 4 + 2] = ((unsigned long long)v.z << 13) | (ib + 2);
            k64[q * 4 + 3] = ((unsigned long long)v.w << 13) | (ib + 3);
        }
    }

    unsigned cnt[8];
#pragma unroll
    for (int jj = 0; jj < 8; ++jj) {
        const int j = bid * 8 + jj;                          // block-uniform
        const unsigned long long th = ((unsigned long long)ENC[j] << 13) | (unsigned)j;
        unsigned cjj = 0;
#pragma unroll
        for (int q = 0; q < 32; ++q) cjj += (unsigned)(k64[q] < th);
        cnt[jj] = cjj;
    }
#pragma unroll
    for (int jj = 0; jj < 8; ++jj) {
        unsigned v = cnt[jj];
#pragma unroll
        for (int m = 32; m >= 1; m >>= 1) v += (unsigned)__shfl_xor((int)v, m, 64);
        cnt[jj] = v;
    }
    const int w = tid >> 6;
    if ((tid & 63) == 0) {
#pragma unroll
        for (int jj = 0; jj < 8; ++jj) cw[w * 8 + jj] = cnt[jj];
    }
    __syncthreads();
    if (tid < 8) {
        const unsigned r = cw[tid] + cw[8 + tid] + cw[16 + tid] + cw[24 + tid];
        const int j = bid * 8 + tid;
        SF2[r] = dec_f32(ENC[j]);
        PERM[r] = j;
    }
}

// kC34: chunk sums (512 chunks x 16) + in-LDS scan. 65 blocks x 1024 threads.
// Block cb<64 owns output column cb, gathering from column-major HT (full
// line utilization); block 64 owns scalar sums AND packs SPQJ float4 + cs.
__global__ __launch_bounds__(1024) void kC34(
    const float* __restrict__ HT, const float* __restrict__ SF2, const int* __restrict__ PERM,
    float4* __restrict__ SPQJ, float* __restrict__ CHPx, float* __restrict__ CHQx,
    float* __restrict__ cs)
{
    __shared__ float preP[1024], preQ[1024];
    __shared__ float scP[NCH], scQ[NCH];
    const int t = threadIdx.x, cb = blockIdx.x;
    const float fm = SF2[NR - 1];
    float accP = 0.f, accQ = 0.f;

    const float4* S4 = (const float4*)(SF2 + t * 8);
    const int4*   P4 = (const int4*)(PERM + t * 8);
    float4 f0 = S4[0], f1v = S4[1];
    int4   j0 = P4[0], j1 = P4[1];
    float sv[8] = { f0.x, f0.y, f0.z, f0.w, f1v.x, f1v.y, f1v.z, f1v.w };
    int   jx[8] = { j0.x, j0.y, j0.z, j0.w, j1.x, j1.y, j1.z, j1.w };

    if (cb < 64) {
        const float* __restrict__ hcol = HT + cb * NR;
#pragma unroll
        for (int e = 0; e < 8; ++e) {
            const float d = sv[e] - fm;
            const float P = __expf(d), Q = __expf(ALPHA * d);
            const float hv = hcol[jx[e]];
            accP = fmaf(P, hv, accP);
            accQ = fmaf(Q, hv, accQ);
        }
    } else {
#pragma unroll
        for (int e = 0; e < 8; ++e) {
            const float d = sv[e] - fm;
            const float P = __expf(d), Q = __expf(ALPHA * d);
            SPQJ[t * 8 + e] = make_float4(sv[e], P, Q, __int_as_float(jx[e]));
            accP += P; accQ += Q;
        }
        if (t < NCH) cs[t] = SF2[t * CSZ];
    }

    preP[t] = accP; preQ[t] = accQ;
    __syncthreads();
    if (t < NCH) {                       // chunk t = threads 2t, 2t+1
        scP[t] = preP[2 * t] + preP[2 * t + 1];
        scQ[t] = preQ[2 * t] + preQ[2 * t + 1];
    }
    __syncthreads();
    for (int off = 1; off < NCH; off <<= 1) {
        float uP = 0.f, uQ = 0.f;
        if (t < NCH && t >= off) { uP = scP[t - off]; uQ = scQ[t - off]; }
        __syncthreads();
        if (t < NCH) { scP[t] += uP; scQ[t] += uQ; }
        __syncthreads();
    }
    if (t < NCH) {
        const float eP = (t > 0) ? scP[t - 1] : 0.f;     // exclusive
        const float eQ = (t > 0) ? scQ[t - 1] : 0.f;
        CHPx[t * 65 + cb] = eP;
        CHQx[t * 65 + cb] = eQ;
        if (t == NCH - 1) { CHPx[NCH * 65 + cb] = scP[t]; CHQx[NCH * 65 + cb] = scQ[t]; }
    }
}

// kD: per-row bsearch (cs in LDS, 9 steps) + 16-elem exact predicated correction
// (one SPQJ float4 per element) + elu. 2048 blocks x 4 rows (1 row/wave).
__global__ __launch_bounds__(256) void kD(
    const float* __restrict__ H, const float* __restrict__ F1, const float* __restrict__ SF2,
    const float4* __restrict__ SPQJ, const float* __restrict__ CHPx,
    const float* __restrict__ CHQx, const float* __restrict__ cs, float* __restrict__ OUT)
{
    __shared__ float sb[NCH];
    const int tid = threadIdx.x, w = tid >> 6, c = tid & 63, bid = blockIdx.x;
    sb[tid] = cs[tid];
    sb[256 + tid] = cs[256 + tid];
    __syncthreads();

    const float fm = SF2[NR - 1];
    const float Ptot = CHPx[NCH * 65 + c], ptot = CHPx[NCH * 65 + 64];
    const int i = bid * 4 + w;

    const float f1 = F1[i];
    const float s = f1 + fm;
    const float mrow = fmaxf(s, ALPHA * s);
    const float A = __expf(s - mrow);
    const float B = __expf(ALPHA * s - mrow);
    const float th = -f1;

    int lo = 0, hi = NCH;
    while (lo < hi) { int mid = (lo + hi) >> 1; if (sb[mid] < th) lo = mid + 1; else hi = mid; }
    const int b = lo > 0 ? lo - 1 : 0;
    const int t0 = b * CSZ;

    float qv = CHQx[b * 65 + c],  pp = CHPx[b * 65 + c];
    float qs = CHQx[b * 65 + 64], ps = CHPx[b * 65 + 64];
#pragma unroll
    for (int tt = 0; tt < CSZ; ++tt) {
        const float4 v = SPQJ[t0 + tt];         // wave-uniform 16B broadcast
        const int jv = __float_as_int(v.w);
        const float hv = H[jv * 64 + c];        // coalesced 256B row
        const bool cd = v.x < th;
        const float cP = cd ? v.y : 0.f, cQ = cd ? v.z : 0.f;
        qv = fmaf(cQ, hv, qv); qs += cQ;
        pp = fmaf(cP, hv, pp); ps += cP;
    }
    const float Pvec = Ptot - pp;
    const float pden = ptot - ps;
    const float num = A * Pvec + B * qv;
    const float den = A * pden + B * qs;
    const float feat = num / den;
    OUT[i * 64 + c] = feat > 0.f ? feat : expm1f(feat);
}

extern "C" void kernel_launch(void* const* d_in, const int* in_sizes, int n_in,
                              void* d_out, int out_size, void* d_ws, size_t ws_size,
                              hipStream_t stream) {
    const float* X = (const float*)d_in[0];   // 8192 x 128
    const float* W = (const float*)d_in[1];   // 128 x 64
    const float* a = (const float*)d_in[2];   // 128 x 1
    float* OUT = (float*)d_out;               // 8192 x 64

    float*    ws   = (float*)d_ws;
    float*    H    = ws;                         // 524288
    float*    HT   = H + 524288;                 // 524288 (column-major)
    float*    F1   = HT + 524288;                // 8192
    unsigned* ENC  = (unsigned*)(F1 + 8192);     // 8192
    float*    SF2  = (float*)(ENC + 8192);       // 8192
    int*      PERM = (int*)(SF2 + 8192);         // 8192
    float4*   SPQJ = (float4*)(PERM + 8192);     // 8192 float4 (16B-aligned)
    float*    CHPx = (float*)(SPQJ + 8192);      // 513*65
    float*    CHQx = CHPx + 513 * 65;            // 513*65
    float*    cs   = CHQx + 513 * 65;            // 512

    kA  <<<512,  256,  0, stream>>>(X, W, a, H, HT, F1, ENC);
    kB  <<<1024, 256,  0, stream>>>(ENC, SF2, PERM);
    kC34<<<65,   1024, 0, stream>>>(HT, SF2, PERM, SPQJ, CHPx, CHQx, cs);
    kD  <<<2048, 256,  0, stream>>>(H, F1, SF2, SPQJ, CHPx, CHQx, cs, OUT);
}